// Round 12
// baseline (832.161 us; speedup 1.0000x reference)
//
#include <hip/hip_runtime.h>

#define CC 256      // checks
#define VV 512      // variables
#define MAXRD 26    // row-degree cap (validated rounds 0-11, absmax 0)
#define MAXCD 18    // col-degree cap (validated)
#define PSTRIDE 27  // deg+1 <= 27 prefix states
#define CLU 6       // fixed-unroll gather depth (tail loop for cd>6)

typedef __attribute__((address_space(1))) float gfloat;   // true global ops (vmcnt only)

__device__ __forceinline__ float sgnf(float x) {
    return (x > 0.f) ? 1.f : ((x < 0.f) ? -1.f : 0.f);
}
// hot-path phi: 2*atan(exp(x/2)), branchless, ~25 instr (validated r11, absmax 0)
__device__ __forceinline__ float fast_phi(float x) {
    const float t  = 0.5f * x;
    const float a  = __expf(-fabsf(t));                    // (0,1]
    const bool  big = a > 0.41421356f;                     // tan(pi/8)
    const float zr  = (a - 1.0f) * __builtin_amdgcn_rcpf(a + 1.0f);
    const float z   = big ? zr : a;                        // |z| <= 0.4142
    const float z2  = z * z;
    float p = 8.05374449538e-2f;
    p = p * z2 - 1.38776856032e-1f;
    p = p * z2 + 1.99777106478e-1f;
    p = p * z2 - 3.33329491539e-1f;
    float r = z + z * (z2 * p);                            // atan(z)
    if (big) r += 0.78539816339f;                          // + pi/4
    return (x >= 0.0f) ? (3.14159265359f - 2.0f * r) : (2.0f * r);
}
__device__ __forceinline__ float fast_tanh(float y) {      // y in (0, pi/2)
    return 1.0f - 2.0f * __builtin_amdgcn_rcpf(__expf(2.0f * y) + 1.0f);
}
// LDS-only fence + raw barrier (no flat ops anywhere -> lgkmcnt is pure LDS)
__device__ __forceinline__ void lds_barrier() {
    asm volatile("s_waitcnt lgkmcnt(0)" ::: "memory");
    __builtin_amdgcn_sched_barrier(0);
    __builtin_amdgcn_s_barrier();
    __builtin_amdgcn_sched_barrier(0);
}

__global__ __launch_bounds__(256)
void ldpc_bp12(const float* __restrict__ llr_g, const int* __restrict__ H_g,
               const int* __restrict__ it_g, int* __restrict__ out_g,
               float* __restrict__ ws)
{
    __shared__ float              llr_s[VV];          //  2048 B
    __shared__ unsigned int       rsign[CC];          //  1024 B
    __shared__ unsigned int       rzero[CC];          //  1024 B
    __shared__ unsigned short     rdeg_s[CC];         //   512 B
    __shared__ float              Pst[CC][PSTRIDE];   // 27648 B
    __shared__ unsigned short     clistT[MAXCD][CC];  //  9216 B (pad=256)
    __shared__ unsigned short     cdeg_s[CC];         //   512 B
    __shared__ float              colbuf[2][257];     //  2056 B  [.][256]=+0.0 pad
    __shared__ float              ring[8][CC];        //  8192 B
    __shared__ unsigned long long rowmask[CC][4];     //  8192 B
    __shared__ unsigned char      rowpre[CC][4];      //  1024 B
    // total 61,448 B < 64 KB static

    const int j  = threadIdx.x;
    const int wv = j >> 6, ln = j & 63;
    gfloat* __restrict__ mg = (gfloat*)ws;  // [thread][c]: val of thread at step == c (mod 256)

    // ---- setup (validated lineage) ----
    llr_s[j] = llr_g[j]; llr_s[j + CC] = llr_g[j + CC];
    __syncthreads();
    {   int d = 0; unsigned int sb = 0, zb = 0;
        const int4* hrow = (const int4*)(H_g + j * VV);
        for (int g = 0; g < VV / 4; ++g) {
            int4 h = hrow[g]; const int v = g * 4;
            if (h.x) { if (d < MAXRD) { float l = llr_s[v+0]; sb |= (l < 0.f) << d; zb |= (l == 0.f) << d; } ++d; }
            if (h.y) { if (d < MAXRD) { float l = llr_s[v+1]; sb |= (l < 0.f) << d; zb |= (l == 0.f) << d; } ++d; }
            if (h.z) { if (d < MAXRD) { float l = llr_s[v+2]; sb |= (l < 0.f) << d; zb |= (l == 0.f) << d; } ++d; }
            if (h.w) { if (d < MAXRD) { float l = llr_s[v+3]; sb |= (l < 0.f) << d; zb |= (l == 0.f) << d; } ++d; }
        }
        rdeg_s[j] = (unsigned short)(d < MAXRD ? d : MAXRD);
        rsign[j] = sb; rzero[j] = zb;
    }
    {   int d = 0;
        for (int c = 0; c < CC; ++c) {
            const int h = H_g[c * VV + j];
            const unsigned long long m = __ballot(h != 0);
            if (ln == 0) rowmask[c][wv] = m;
            if (h) { if (d < MAXCD) clistT[d][j] = (unsigned short)c; ++d; }
        }
        cdeg_s[j] = (unsigned short)(d < MAXCD ? d : MAXCD);
        for (int k = d; k < MAXCD; ++k) clistT[k][j] = 256;
    }
    colbuf[0][j] = 0.0f;
    #pragma unroll
    for (int r = 0; r < 8; ++r) ring[r][j] = 0.0f;
    if (j == 0) { colbuf[0][256] = 0.0f; colbuf[1][256] = 0.0f; }
    __syncthreads();
    {   const int p1 = __popcll(rowmask[j][0]);
        const int p2 = p1 + __popcll(rowmask[j][1]);
        const int p3 = p2 + __popcll(rowmask[j][2]);
        rowpre[j][0] = 0; rowpre[j][1] = (unsigned char)p1;
        rowpre[j][2] = (unsigned char)p2; rowpre[j][3] = (unsigned char)p3;
    }
    const int cl0 = clistT[0][j], cl1 = clistT[1][j], cl2 = clistT[2][j];
    const int cl3 = clistT[3][j], cl4 = clistT[4][j], cl5 = clistT[5][j];
    const int cd  = cdeg_s[j];
    __syncthreads();

    const int   max_iter = it_g[0];
    const int   total    = max_iter * CC;
    const float T05      = tanhf(0.5f);
    const float sgj      = sgnf(llr_s[j]);

    float sv_base = 0.f, sv_bi = 0.f, sv_cbs = 0.f;
    int   sv_hv = 0;
    float val_prev = 0.f, fprod = 1.0f;

    auto STEP = [&](int T, float& pf_issue, float& pf_use) {
        const int s   = T & 255;
        const int Tc  = T + 1;
        const int X1  = Tc & 255;
        const int sfx = (T >= 1) ? ((T - 1) & 255) : -1;     // raw-cell index (-1 = none)

        // ---- early issues: all loads first; latencies hide under (a)'s phi ----
        const float* cb = colbuf[T & 1];
        const float g0 = cb[cl0], g1 = cb[cl1], g2 = cb[cl2];
        const float g3 = cb[cl3], g4 = cb[cl4], g5 = cb[cl5];
        const float craw = cb[sfx < 0 ? 0 : sfx];            // raw arg of fresh cell
        const unsigned long long rm = rowmask[s][wv];
        const int   p     = T - ((T - j) & 255);             // last step == j (mod 256)
        const float ringv = ring[p & 7][X1];                 // slot (T-1)&7 not read ✓
        pf_issue = mg[((T + 4) & 255) * CC + j];             // global prefetch (vmcnt only)

        // ---- (a) deferred finish of step T-1 (register-only compute) ----
        if (T > 0) {
            float vnp;
            if (sv_hv) { float vnew = fast_phi(sv_bi); vnp = fast_phi(sv_base + (vnew - sv_cbs)); }
            else       vnp = fast_phi(sv_base);
            val_prev = vnp;
            ring[(T - 1) & 7][j] = vnp;
            mg[j * CC + ((T - 1) & 255)] = vnp;              // global fire-and-forget
            if (j < 4 && (T - 1) >= total - CC) fprod *= fast_tanh(0.5f * vnp);
        }

        // ---- (d) p1 at pass start (thread = check j; cold, keeps libm) ----
        if (s == 0) {
            const int pass = T >> 8;
            const int deg  = rdeg_s[j];
            const unsigned int sb = rsign[j], zb = rzero[j];
            float NP = 1.0f;
            for (int k = 0; k <= deg; ++k) {
                float P = NP;
                for (int idx = k; idx < deg; ++idx) {        // old tail, ascending v
                    float told;
                    if (pass == 0) told = T05;
                    else {
                        const float sg = ((zb >> idx) & 1u) ? 0.0f
                                       : (((sb >> idx) & 1u) ? -1.0f : 1.0f);
                        told = tanhf(0.5f * (sg * Pst[j][idx]));
                    }
                    P *= told;
                }
                Pst[j][k] = P;                               // in-place safe (idx >= k)
                if (k < deg) {
                    const float sg = ((zb >> k) & 1u) ? 0.0f
                                   : (((sb >> k) & 1u) ? -1.0f : 1.0f);
                    NP *= tanhf(0.5f * (sg * P));
                }
            }
            lds_barrier();
        }

        // ---- (g) stage colbuf for consumer Tc: zero / ring / prefetched global ----
        if (Tc < total && p <= T - 2) {                      // p in {T,T-1}: owner patches
            float v;
            if (p < 0)           v = 0.0f;                   // pass-0 initial (first!)
            else if (p >= T - 8) v = ringv;                  // ring (phi'd)
            else                 v = pf_use;                 // global, >=10 steps old
            colbuf[Tc & 1][j] = v;
        }

        // ---- (h) compute step T; raw fresh cell phi'd only by threads that need it ----
        const int  kj  = (int)rowpre[s][wv] + __popcll(rm & ((1ull << ln) - 1ull));
        const bool hit = (rm >> ln) & 1ull;
        const bool hv  = hit && (j > s);
        bool need = (cl0 == sfx) | (cl1 == sfx) | (cl2 == sfx)
                  | (cl3 == sfx) | (cl4 == sfx) | (cl5 == sfx);
        for (int k = CLU; k < cd; ++k) need |= ((int)clistT[k][j] == sfx);  // rare
        float ph = 0.0f;
        if (need | hv) ph = fast_phi(craw);                  // ~6-9 threads/step

        const float t0 = (cl0 == sfx) ? ph : g0;
        const float t1 = (cl1 == sfx) ? ph : g1;
        const float t2 = (cl2 == sfx) ? ph : g2;
        const float t3 = (cl3 == sfx) ? ph : g3;
        const float t4 = (cl4 == sfx) ? ph : g4;
        const float t5 = (cl5 == sfx) ? ph : g5;
        float sum = 0.0f;                                    // ascending-c, left-assoc
        sum += t0; sum += t1; sum += t2; sum += t3; sum += t4; sum += t5;
        for (int k = CLU; k < cd; ++k) {                     // rare tail
            const int ci = clistT[k][j];
            sum += (ci == sfx) ? ph : cb[ci];
        }
        const float base = sum - sgj * Pst[s][kj];
        float bi = 0.f, cbs = 0.f;
        if (hv) {                                            // ~3 threads/step
            float bsum = 0.0f;
            const int cds = cdeg_s[s];
            for (int k = 0; k < cds; ++k) {
                const int ci = clistT[k][s];
                bsum += (ci == sfx) ? ph : cb[ci];
            }
            const int ki = (int)rowpre[s][s >> 6]
                         + __popcll(rowmask[s][s >> 6] & ((1ull << (s & 63)) - 1ull));
            bi  = bsum - sgnf(llr_s[s]) * Pst[s][ki];
            cbs = cb[s];                                     // s != sfx ✓ (phi'd, old)
        }
        sv_base = base; sv_bi = bi; sv_cbs = cbs; sv_hv = hv ? 1 : 0;

        // owner thread X1: store RAW arg (no phi on chain); patch T-1 (phi'd, ready early)
        if (Tc < total && j == X1) {
            float rawv;
            if (hv) { float vnew = fast_phi(bi); rawv = base + (vnew - cbs); }
            else    rawv = base;                             // common case: no phi at all
            colbuf[Tc & 1][s] = rawv;                        // producer T (raw)
            colbuf[Tc & 1][(T - 1) & 255] = val_prev;        // producer T-1 (phi'd)
        }

        lds_barrier();                                       // LDS-only end barrier
    };

    float p0 = 0.f, p1r = 0.f, p2r = 0.f, p3r = 0.f;         // 4-slot prefetch rotation
    #pragma unroll 1
    for (int T4 = 0; T4 < total; T4 += 4) {                  // total % 4 == 0
        STEP(T4 + 0, p0,  p1r);
        STEP(T4 + 1, p1r, p2r);
        STEP(T4 + 2, p2r, p3r);
        STEP(T4 + 3, p3r, p0);
    }

    // epilogue: deferred phi of step total-1, then output (threads 0..3)
    {
        float vnp;
        if (sv_hv) { float vnew = fast_phi(sv_bi); vnp = fast_phi(sv_base + (vnew - sv_cbs)); }
        else       vnp = fast_phi(sv_base);
        if (j < 4) {
            fprod *= fast_tanh(0.5f * vnp);                  // step total-1 (c = 255)
            const float soft = sgj * fprod;
            out_g[j] = (soft > 0.0f) ? 1 : 0;
        }
    }
}

extern "C" void kernel_launch(void* const* d_in, const int* in_sizes, int n_in,
                              void* d_out, int out_size, void* d_ws, size_t ws_size,
                              hipStream_t stream) {
    const float* llr = (const float*)d_in[0];
    const int*   H   = (const int*)d_in[1];
    const int*   mi  = (const int*)d_in[2];
    int*         out = (int*)d_out;
    float*       ws  = (float*)d_ws;
    hipLaunchKernelGGL(ldpc_bp12, dim3(1), dim3(256), 0, stream,
                       llr, H, mi, out, ws);
}

// Round 13
// 536.039 us; speedup vs baseline: 1.5524x; 1.5524x over previous
//
#include <hip/hip_runtime.h>

#define CC 256      // checks
#define VV 512      // variables
#define MAXRD 26    // row-degree cap (validated rounds 0-12, absmax 0)
#define MAXCD 18    // col-degree cap (validated)
#define PSTRIDE 27  // deg+1 <= 27 prefix states
#define CLU 6       // fixed-unroll gather depth (tail loop for cd>6)

typedef __attribute__((address_space(1))) float gfloat;   // true global ops (vmcnt only)

__device__ __forceinline__ float sgnf(float x) {
    return (x > 0.f) ? 1.f : ((x < 0.f) ? -1.f : 0.f);
}
// hot-path phi: 2*atan(exp(x/2)), branchless, ~25 instr (validated r11, absmax 0)
__device__ __forceinline__ float fast_phi(float x) {
    const float t  = 0.5f * x;
    const float a  = __expf(-fabsf(t));                    // (0,1]
    const bool  big = a > 0.41421356f;                     // tan(pi/8)
    const float zr  = (a - 1.0f) * __builtin_amdgcn_rcpf(a + 1.0f);
    const float z   = big ? zr : a;                        // |z| <= 0.4142
    const float z2  = z * z;
    float p = 8.05374449538e-2f;
    p = p * z2 - 1.38776856032e-1f;
    p = p * z2 + 1.99777106478e-1f;
    p = p * z2 - 3.33329491539e-1f;
    float r = z + z * (z2 * p);                            // atan(z)
    if (big) r += 0.78539816339f;                          // + pi/4
    return (x >= 0.0f) ? (3.14159265359f - 2.0f * r) : (2.0f * r);
}
__device__ __forceinline__ float fast_tanh(float y) {      // y in (0, pi/2)
    return 1.0f - 2.0f * __builtin_amdgcn_rcpf(__expf(2.0f * y) + 1.0f);
}
// LDS-only fence + raw barrier (no flat ops anywhere -> lgkmcnt is pure LDS)
__device__ __forceinline__ void lds_barrier() {
    asm volatile("s_waitcnt lgkmcnt(0)" ::: "memory");
    __builtin_amdgcn_sched_barrier(0);
    __builtin_amdgcn_s_barrier();
    __builtin_amdgcn_sched_barrier(0);
}

__global__ __launch_bounds__(256)
void ldpc_bp13(const float* __restrict__ llr_g, const int* __restrict__ H_g,
               const int* __restrict__ it_g, int* __restrict__ out_g,
               float* __restrict__ ws)
{
    __shared__ float              llr_s[VV];          //  2048 B
    __shared__ unsigned int       rsign[CC];          //  1024 B
    __shared__ unsigned int       rzero[CC];          //  1024 B
    __shared__ unsigned short     rdeg_s[CC];         //   512 B
    __shared__ float              Pst[CC][PSTRIDE];   // 27648 B
    __shared__ unsigned short     clistT[MAXCD][CC];  //  9216 B (pad=256)
    __shared__ unsigned short     cdeg_s[CC];         //   512 B
    __shared__ float              colbuf[2][257];     //  2056 B  [.][256]=+0.0 pad
    __shared__ float              ring[8][CC];        //  8192 B
    __shared__ unsigned long long rowmask[CC][4];     //  8192 B
    __shared__ unsigned char      rowpre[CC][4];      //  1024 B
    // total 61,448 B < 64 KB static

    const int j  = threadIdx.x;
    const int wv = j >> 6, ln = j & 63;
    gfloat* __restrict__ mg = (gfloat*)ws;  // [thread][c]: val of thread at step == c (mod 256)

    // ---- setup (validated lineage) ----
    llr_s[j] = llr_g[j]; llr_s[j + CC] = llr_g[j + CC];
    __syncthreads();
    {   int d = 0; unsigned int sb = 0, zb = 0;
        const int4* hrow = (const int4*)(H_g + j * VV);
        for (int g = 0; g < VV / 4; ++g) {
            int4 h = hrow[g]; const int v = g * 4;
            if (h.x) { if (d < MAXRD) { float l = llr_s[v+0]; sb |= (l < 0.f) << d; zb |= (l == 0.f) << d; } ++d; }
            if (h.y) { if (d < MAXRD) { float l = llr_s[v+1]; sb |= (l < 0.f) << d; zb |= (l == 0.f) << d; } ++d; }
            if (h.z) { if (d < MAXRD) { float l = llr_s[v+2]; sb |= (l < 0.f) << d; zb |= (l == 0.f) << d; } ++d; }
            if (h.w) { if (d < MAXRD) { float l = llr_s[v+3]; sb |= (l < 0.f) << d; zb |= (l == 0.f) << d; } ++d; }
        }
        rdeg_s[j] = (unsigned short)(d < MAXRD ? d : MAXRD);
        rsign[j] = sb; rzero[j] = zb;
    }
    {   int d = 0;
        for (int c = 0; c < CC; ++c) {
            const int h = H_g[c * VV + j];
            const unsigned long long m = __ballot(h != 0);
            if (ln == 0) rowmask[c][wv] = m;
            if (h) { if (d < MAXCD) clistT[d][j] = (unsigned short)c; ++d; }
        }
        cdeg_s[j] = (unsigned short)(d < MAXCD ? d : MAXCD);
        for (int k = d; k < MAXCD; ++k) clistT[k][j] = 256;
    }
    colbuf[0][j] = 0.0f;
    #pragma unroll
    for (int r = 0; r < 8; ++r) ring[r][j] = 0.0f;
    if (j == 0) { colbuf[0][256] = 0.0f; colbuf[1][256] = 0.0f; }
    __syncthreads();
    {   const int p1 = __popcll(rowmask[j][0]);
        const int p2 = p1 + __popcll(rowmask[j][1]);
        const int p3 = p2 + __popcll(rowmask[j][2]);
        rowpre[j][0] = 0; rowpre[j][1] = (unsigned char)p1;
        rowpre[j][2] = (unsigned char)p2; rowpre[j][3] = (unsigned char)p3;
    }
    const int cl0 = clistT[0][j], cl1 = clistT[1][j], cl2 = clistT[2][j];
    const int cl3 = clistT[3][j], cl4 = clistT[4][j], cl5 = clistT[5][j];
    const int cd  = cdeg_s[j];
    __syncthreads();

    const int   max_iter = it_g[0];
    const int   total    = max_iter * CC;
    const float T05      = tanhf(0.5f);
    const float sgj      = sgnf(llr_s[j]);
    const unsigned long long lanelt = (1ull << ln) - 1ull;

    float sv_base = 0.f, sv_bi = 0.f, sv_cbs = 0.f;
    int   sv_hv = 0;
    float val_prev = 0.f, fprod = 1.0f;

    // carried next-step prefetch (valid for consumer steps with s != 0)
    int   ckj = 0, cki = 0; bool chit = false;
    float cPst = 0.f, cPsti = 0.f;

    auto STEP = [&](int T, float& pf_issue, float& pf_use) {
        const int s  = T & 255;
        const int Tc = T + 1;
        const int X1 = Tc & 255;
        const int sn = Tc & 255;                             // next step's s

        // ---- early issues: this step's gathers + NEXT step's mask/Pst prefetch ----
        const float* cb = colbuf[T & 1];
        const float g0 = cb[cl0], g1 = cb[cl1], g2 = cb[cl2];
        const float g3 = cb[cl3], g4 = cb[cl4], g5 = cb[cl5];
        const int   p     = T - ((T - j) & 255);             // last step == j (mod 256)
        const float ringv = ring[p & 7][X1];                 // slot (T-1)&7 not read ✓
        pf_issue = mg[((T + 4) & 255) * CC + j];             // global prefetch (vmcnt only)
        const unsigned long long nrm  = rowmask[sn][wv];     // next-step mask (setup-const)
        const unsigned long long nrmw = rowmask[sn][sn >> 6];

        // ---- (a) deferred finish of step T-1 (register-only compute) ----
        if (T > 0) {
            float vnp;
            if (sv_hv) { float vnew = fast_phi(sv_bi); vnp = fast_phi(sv_base + (vnew - sv_cbs)); }
            else       vnp = fast_phi(sv_base);
            val_prev = vnp;
            ring[(T - 1) & 7][j] = vnp;
            mg[j * CC + ((T - 1) & 255)] = vnp;              // global fire-and-forget
            if (j < 4 && (T - 1) >= total - CC) fprod *= fast_tanh(0.5f * vnp);
        }

        // ---- (d) p1 at pass start (thread = check j; cold, keeps libm) ----
        if (s == 0) {
            const int pass = T >> 8;
            const int deg  = rdeg_s[j];
            const unsigned int sb = rsign[j], zb = rzero[j];
            float NP = 1.0f;
            for (int k = 0; k <= deg; ++k) {
                float P = NP;
                for (int idx = k; idx < deg; ++idx) {        // old tail, ascending v
                    float told;
                    if (pass == 0) told = T05;
                    else {
                        const float sg = ((zb >> idx) & 1u) ? 0.0f
                                       : (((sb >> idx) & 1u) ? -1.0f : 1.0f);
                        told = tanhf(0.5f * (sg * Pst[j][idx]));
                    }
                    P *= told;
                }
                Pst[j][k] = P;                               // in-place safe (idx >= k)
                if (k < deg) {
                    const float sg = ((zb >> k) & 1u) ? 0.0f
                                   : (((sb >> k) & 1u) ? -1.0f : 1.0f);
                    NP *= tanhf(0.5f * (sg * P));
                }
            }
            lds_barrier();
        }

        // ---- (g) stage colbuf for consumer Tc: zero / ring / prefetched global ----
        if (Tc < total && p <= T - 2) {                      // p in {T,T-1}: owner patches
            float v;
            if (p < 0)           v = 0.0f;                   // pass-0 initial (first!)
            else if (p >= T - 8) v = ringv;                  // ring (phi'd)
            else                 v = pf_use;                 // global, >=10 steps old
            colbuf[Tc & 1][j] = v;
        }

        // ---- (h) compute step T: kj/hit/Pst from carried prefetch (s!=0) ----
        int kj, ki; bool hit; float PstV, PstiV;
        if (s != 0) {                                        // 510/512 steps: registers
            kj = ckj; hit = chit; PstV = cPst; ki = cki; PstiV = cPsti;
        } else {                                             // pass start: Pst just rebuilt
            const unsigned long long rm  = rowmask[s][wv];
            const unsigned long long rmw = rowmask[s][s >> 6];
            kj  = (int)rowpre[s][wv] + __popcll(rm & lanelt);
            hit = (rm >> ln) & 1ull;
            ki  = (int)rowpre[s][s >> 6] + __popcll(rmw & ((1ull << (s & 63)) - 1ull));
            PstV  = Pst[s][kj];
            PstiV = Pst[s][ki];
        }
        float sum = 0.0f;                                    // ascending-c, left-assoc
        sum += g0; sum += g1; sum += g2; sum += g3; sum += g4; sum += g5;
        for (int k = CLU; k < cd; ++k) sum += cb[clistT[k][j]];   // rare tail
        const float base = sum - sgj * PstV;
        const bool hv = hit && (j > s);
        float bi = 0.f, cbs = 0.f;
        if (hv) {                                            // ~3 threads/step
            float bsum = 0.0f;
            bsum += cb[clistT[0][s]]; bsum += cb[clistT[1][s]];
            bsum += cb[clistT[2][s]]; bsum += cb[clistT[3][s]];
            bsum += cb[clistT[4][s]]; bsum += cb[clistT[5][s]];
            const int cds = cdeg_s[s];
            for (int k = CLU; k < cds; ++k) bsum += cb[clistT[k][s]];
            bi  = bsum - sgnf(llr_s[s]) * PstiV;
            cbs = cb[s];
        }
        sv_base = base; sv_bi = bi; sv_cbs = cbs; sv_hv = hv ? 1 : 0;

        // ---- prefetch state for step T+1 (rowmask const; Pst stable unless sn==0) ----
        ckj  = (int)rowpre[sn][wv] + __popcll(nrm & lanelt);
        chit = (nrm >> ln) & 1ull;
        cki  = (int)rowpre[sn][sn >> 6] + __popcll(nrmw & ((1ull << (sn & 63)) - 1ull));
        cPst  = Pst[sn][ckj];                                // stale iff sn==0 (unused then)
        cPsti = Pst[sn][cki];

        // owner thread X1: its val feeds next column -> fast phi inline + patch
        if (Tc < total && j == X1) {
            float vo;
            if (hv) { float vnew = fast_phi(bi); vo = fast_phi(base + (vnew - cbs)); }
            else    vo = fast_phi(base);
            colbuf[Tc & 1][s] = vo;                          // producer T (phi'd)
            colbuf[Tc & 1][(T - 1) & 255] = val_prev;        // producer T-1 (own)
        }

        lds_barrier();                                       // LDS-only end barrier
    };

    float p0 = 0.f, p1r = 0.f, p2r = 0.f, p3r = 0.f;         // 4-slot prefetch rotation
    #pragma unroll 1
    for (int T4 = 0; T4 < total; T4 += 4) {                  // total % 4 == 0
        STEP(T4 + 0, p0,  p1r);
        STEP(T4 + 1, p1r, p2r);
        STEP(T4 + 2, p2r, p3r);
        STEP(T4 + 3, p3r, p0);
    }

    // epilogue: deferred phi of step total-1, then output (threads 0..3)
    {
        float vnp;
        if (sv_hv) { float vnew = fast_phi(sv_bi); vnp = fast_phi(sv_base + (vnew - sv_cbs)); }
        else       vnp = fast_phi(sv_base);
        if (j < 4) {
            fprod *= fast_tanh(0.5f * vnp);                  // step total-1 (c = 255)
            const float soft = sgj * fprod;
            out_g[j] = (soft > 0.0f) ? 1 : 0;
        }
    }
}

extern "C" void kernel_launch(void* const* d_in, const int* in_sizes, int n_in,
                              void* d_out, int out_size, void* d_ws, size_t ws_size,
                              hipStream_t stream) {
    const float* llr = (const float*)d_in[0];
    const int*   H   = (const int*)d_in[1];
    const int*   mi  = (const int*)d_in[2];
    int*         out = (int*)d_out;
    float*       ws  = (float*)d_ws;
    hipLaunchKernelGGL(ldpc_bp13, dim3(1), dim3(256), 0, stream,
                       llr, H, mi, out, ws);
}

// Round 14
// 514.715 us; speedup vs baseline: 1.6167x; 1.0414x over previous
//
#include <hip/hip_runtime.h>

#define CC 256      // checks
#define VV 512      // variables
#define MAXRD 26    // row-degree cap (validated rounds 0-13, absmax 0)
#define MAXCD 18    // col-degree cap (validated)
#define PSTRIDE 27  // deg+1 <= 27 prefix states
#define CLU 6       // fixed-unroll gather depth (tail loop for cd>6)

typedef __attribute__((address_space(1))) float gfloat;   // true global ops (vmcnt only)

__device__ __forceinline__ float sgnf(float x) {
    return (x > 0.f) ? 1.f : ((x < 0.f) ? -1.f : 0.f);
}
// hot-path phi: 2*atan(exp(x/2)), branchless, ~25 instr (validated r11, absmax 0)
__device__ __forceinline__ float fast_phi(float x) {
    const float t  = 0.5f * x;
    const float a  = __expf(-fabsf(t));                    // (0,1]
    const bool  big = a > 0.41421356f;                     // tan(pi/8)
    const float zr  = (a - 1.0f) * __builtin_amdgcn_rcpf(a + 1.0f);
    const float z   = big ? zr : a;                        // |z| <= 0.4142
    const float z2  = z * z;
    float p = 8.05374449538e-2f;
    p = p * z2 - 1.38776856032e-1f;
    p = p * z2 + 1.99777106478e-1f;
    p = p * z2 - 3.33329491539e-1f;
    float r = z + z * (z2 * p);                            // atan(z)
    if (big) r += 0.78539816339f;                          // + pi/4
    return (x >= 0.0f) ? (3.14159265359f - 2.0f * r) : (2.0f * r);
}
__device__ __forceinline__ float fast_tanh(float y) {      // y in (0, pi/2)
    return 1.0f - 2.0f * __builtin_amdgcn_rcpf(__expf(2.0f * y) + 1.0f);
}
// LDS-only fence + raw barrier (no flat ops anywhere -> lgkmcnt is pure LDS)
__device__ __forceinline__ void lds_barrier() {
    asm volatile("s_waitcnt lgkmcnt(0)" ::: "memory");
    __builtin_amdgcn_sched_barrier(0);
    __builtin_amdgcn_s_barrier();
    __builtin_amdgcn_sched_barrier(0);
}

__global__ __launch_bounds__(256)
void ldpc_bp14(const float* __restrict__ llr_g, const int* __restrict__ H_g,
               const int* __restrict__ it_g, int* __restrict__ out_g,
               float* __restrict__ ws)
{
    __shared__ float              llr_s[VV];          //  2048 B
    __shared__ unsigned int       rsign[CC];          //  1024 B
    __shared__ unsigned int       rzero[CC];          //  1024 B
    __shared__ unsigned short     rdeg_s[CC];         //   512 B
    __shared__ float              Pst[CC][PSTRIDE];   // 27648 B
    __shared__ unsigned short     clistT[MAXCD][CC];  //  9216 B (pad=256)
    __shared__ unsigned short     cdeg_s[CC];         //   512 B
    __shared__ float              colbuf[2][257];     //  2056 B  [.][256]=+0.0 pad
    __shared__ float              ring[8][CC];        //  8192 B
    __shared__ unsigned long long rowmask[CC][4];     //  8192 B
    __shared__ unsigned char      rowpre[CC][4];      //  1024 B
    // total 61,448 B < 64 KB static

    const int j  = threadIdx.x;
    const int wv = j >> 6, ln = j & 63;
    gfloat* __restrict__ mg = (gfloat*)ws;  // [thread][c]: val of thread at step == c (mod 256)

    // ---- setup (validated lineage) ----
    llr_s[j] = llr_g[j]; llr_s[j + CC] = llr_g[j + CC];
    __syncthreads();
    {   int d = 0; unsigned int sb = 0, zb = 0;
        const int4* hrow = (const int4*)(H_g + j * VV);
        for (int g = 0; g < VV / 4; ++g) {
            int4 h = hrow[g]; const int v = g * 4;
            if (h.x) { if (d < MAXRD) { float l = llr_s[v+0]; sb |= (l < 0.f) << d; zb |= (l == 0.f) << d; } ++d; }
            if (h.y) { if (d < MAXRD) { float l = llr_s[v+1]; sb |= (l < 0.f) << d; zb |= (l == 0.f) << d; } ++d; }
            if (h.z) { if (d < MAXRD) { float l = llr_s[v+2]; sb |= (l < 0.f) << d; zb |= (l == 0.f) << d; } ++d; }
            if (h.w) { if (d < MAXRD) { float l = llr_s[v+3]; sb |= (l < 0.f) << d; zb |= (l == 0.f) << d; } ++d; }
        }
        rdeg_s[j] = (unsigned short)(d < MAXRD ? d : MAXRD);
        rsign[j] = sb; rzero[j] = zb;
    }
    {   int d = 0;
        for (int c = 0; c < CC; ++c) {
            const int h = H_g[c * VV + j];
            const unsigned long long m = __ballot(h != 0);
            if (ln == 0) rowmask[c][wv] = m;
            if (h) { if (d < MAXCD) clistT[d][j] = (unsigned short)c; ++d; }
        }
        cdeg_s[j] = (unsigned short)(d < MAXCD ? d : MAXCD);
        for (int k = d; k < MAXCD; ++k) clistT[k][j] = 256;
    }
    colbuf[0][j] = 0.0f;
    #pragma unroll
    for (int r = 0; r < 8; ++r) ring[r][j] = 0.0f;
    if (j == 0) { colbuf[0][256] = 0.0f; colbuf[1][256] = 0.0f; }
    __syncthreads();
    {   const int p1 = __popcll(rowmask[j][0]);
        const int p2 = p1 + __popcll(rowmask[j][1]);
        const int p3 = p2 + __popcll(rowmask[j][2]);
        rowpre[j][0] = 0; rowpre[j][1] = (unsigned char)p1;
        rowpre[j][2] = (unsigned char)p2; rowpre[j][3] = (unsigned char)p3;
    }
    const int cl0 = clistT[0][j], cl1 = clistT[1][j], cl2 = clistT[2][j];
    const int cl3 = clistT[3][j], cl4 = clistT[4][j], cl5 = clistT[5][j];
    const int cd  = cdeg_s[j];
    __syncthreads();

    const int   max_iter = it_g[0];
    const int   total    = max_iter * CC;
    const float T05      = tanhf(0.5f);
    const float sgj      = sgnf(llr_s[j]);

    float sv_base = 0.f, sv_bi = 0.f, sv_cbs = 0.f;
    int   sv_hv = 0;
    float val_prev = 0.f;

    auto STEP = [&](int T, float& pf_issue, float& pf_use) {
        const int s  = T & 255;
        const int Tc = T + 1;
        const int X1 = Tc & 255;

        // ---- early issues: all loads first; latencies hide under (a)'s phi ----
        const float* cb = colbuf[T & 1];
        const float g0 = cb[cl0], g1 = cb[cl1], g2 = cb[cl2];
        const float g3 = cb[cl3], g4 = cb[cl4], g5 = cb[cl5];
        const unsigned long long rm = rowmask[s][wv];
        const int   p     = T - ((T - j) & 255);             // last step == j (mod 256)
        const float ringv = ring[p & 7][X1];                 // slot (T-1)&7 not read ✓
        pf_issue = mg[((T + 4) & 255) * CC + j];             // global prefetch (vmcnt only)

        // ---- (a) deferred finish of step T-1 (register-only compute) ----
        if (T > 0) {
            float vnp;
            if (sv_hv) { float vnew = fast_phi(sv_bi); vnp = fast_phi(sv_base + (vnew - sv_cbs)); }
            else       vnp = fast_phi(sv_base);
            val_prev = vnp;
            ring[(T - 1) & 7][j] = vnp;
            mg[j * CC + ((T - 1) & 255)] = vnp;              // global fire-and-forget
        }

        // ---- (d) p1 at pass start (thread = check j; cold, keeps libm) ----
        if (s == 0) {
            const int pass = T >> 8;
            const int deg  = rdeg_s[j];
            const unsigned int sb = rsign[j], zb = rzero[j];
            float NP = 1.0f;
            for (int k = 0; k <= deg; ++k) {
                float P = NP;
                for (int idx = k; idx < deg; ++idx) {        // old tail, ascending v
                    float told;
                    if (pass == 0) told = T05;
                    else {
                        const float sg = ((zb >> idx) & 1u) ? 0.0f
                                       : (((sb >> idx) & 1u) ? -1.0f : 1.0f);
                        told = tanhf(0.5f * (sg * Pst[j][idx]));
                    }
                    P *= told;
                }
                Pst[j][k] = P;                               // in-place safe (idx >= k)
                if (k < deg) {
                    const float sg = ((zb >> k) & 1u) ? 0.0f
                                   : (((sb >> k) & 1u) ? -1.0f : 1.0f);
                    NP *= tanhf(0.5f * (sg * P));
                }
            }
            lds_barrier();
        }

        // ---- (g) stage colbuf for consumer Tc: zero / ring / prefetched global ----
        if (Tc < total && p <= T - 2) {                      // p in {T,T-1}: owner patches
            float v;
            if (p < 0)           v = 0.0f;                   // pass-0 initial (first!)
            else if (p >= T - 8) v = ringv;                  // ring (phi'd)
            else                 v = pf_use;                 // global, >=10 steps old
            colbuf[Tc & 1][j] = v;
        }

        // ---- (h) compute step T from pre-issued gathers ----
        const int  kj  = (int)rowpre[s][wv] + __popcll(rm & ((1ull << ln) - 1ull));
        const bool hit = (rm >> ln) & 1ull;
        float sum = 0.0f;                                    // ascending-c, left-assoc
        sum += g0; sum += g1; sum += g2; sum += g3; sum += g4; sum += g5;
        for (int k = CLU; k < cd; ++k) sum += cb[clistT[k][j]];   // rare tail
        const float base = sum - sgj * Pst[s][kj];
        const bool hv = hit && (j > s);
        float bi = 0.f, cbs = 0.f;
        if (hv) {                                            // ~3 threads/step
            float bsum = 0.0f;
            bsum += cb[clistT[0][s]]; bsum += cb[clistT[1][s]];
            bsum += cb[clistT[2][s]]; bsum += cb[clistT[3][s]];
            bsum += cb[clistT[4][s]]; bsum += cb[clistT[5][s]];
            const int cds = cdeg_s[s];
            for (int k = CLU; k < cds; ++k) bsum += cb[clistT[k][s]];
            const int ki = (int)rowpre[s][s >> 6]
                         + __popcll(rowmask[s][s >> 6] & ((1ull << (s & 63)) - 1ull));
            bi  = bsum - sgnf(llr_s[s]) * Pst[s][ki];
            cbs = cb[s];
        }
        sv_base = base; sv_bi = bi; sv_cbs = cbs; sv_hv = hv ? 1 : 0;

        // owner thread X1: its val feeds next column -> fast phi inline + patch
        if (Tc < total && j == X1) {
            float vo;
            if (hv) { float vnew = fast_phi(bi); vo = fast_phi(base + (vnew - cbs)); }
            else    vo = fast_phi(base);
            colbuf[Tc & 1][s] = vo;                          // producer T (phi'd)
            colbuf[Tc & 1][(T - 1) & 255] = val_prev;        // producer T-1 (own)
        }

        lds_barrier();                                       // LDS-only end barrier
    };

    float p0 = 0.f, p1r = 0.f, p2r = 0.f, p3r = 0.f;         // 4-slot prefetch rotation
    #pragma unroll 1
    for (int T4 = 0; T4 < total; T4 += 4) {                  // total % 4 == 0
        STEP(T4 + 0, p0,  p1r);
        STEP(T4 + 1, p1r, p2r);
        STEP(T4 + 2, p2r, p3r);
        STEP(T4 + 3, p3r, p0);
    }

    // ---- epilogue: product rebuilt from mg (slots 0..254) + sv (slot 255) ----
    // mg[v*CC + c] holds the LAST pass's step-c value (bitwise the vnp that the
    // removed online product consumed); slot 255 is still in sv registers.
    {
        float vnp;
        if (sv_hv) { float vnew = fast_phi(sv_bi); vnp = fast_phi(sv_base + (vnew - sv_cbs)); }
        else       vnp = fast_phi(sv_base);
        if (j < 4) {
            const gfloat* row = mg + j * CC;
            float prod = 1.0f;
            for (int c = 0; c < CC - 1; ++c)                 // ascending c, left-assoc
                prod *= fast_tanh(0.5f * row[c]);
            prod *= fast_tanh(0.5f * vnp);                   // slot 255 (step total-1)
            const float soft = sgj * prod;
            out_g[j] = (soft > 0.0f) ? 1 : 0;
        }
    }
}

extern "C" void kernel_launch(void* const* d_in, const int* in_sizes, int n_in,
                              void* d_out, int out_size, void* d_ws, size_t ws_size,
                              hipStream_t stream) {
    const float* llr = (const float*)d_in[0];
    const int*   H   = (const int*)d_in[1];
    const int*   mi  = (const int*)d_in[2];
    int*         out = (int*)d_out;
    float*       ws  = (float*)d_ws;
    hipLaunchKernelGGL(ldpc_bp14, dim3(1), dim3(256), 0, stream,
                       llr, H, mi, out, ws);
}